// Round 12
// baseline (442.600 us; speedup 1.0000x reference)
//
#include <hip/hip_runtime.h>
#include <hip/hip_bf16.h>
#include <stdint.h>

#define Bz 2
#define Nz 2048
#define Cz 512
#define Hz 8
#define Kz 256
#define Lz 2
#define Dz 64
#define FFz 2048
#define BN_ROWS (Bz*Nz)          // 4096
#define XELEMS  (BN_ROWS*Cz)     // 2097152

typedef __attribute__((ext_vector_type(8))) short bf16x8;
typedef __attribute__((ext_vector_type(4))) float f32x4;
typedef unsigned short u16;

static __device__ __forceinline__ u16 f2bf(float f) {
    union { float f; uint32_t u; } v; v.f = f;
    return (u16)((v.u + 0x7FFFu + ((v.u >> 16) & 1u)) >> 16);
}
static __device__ __forceinline__ float bf2f(u16 h) {
    union { uint32_t u; float f; } v; v.u = ((uint32_t)h) << 16;
    return v.f;
}

// global -> LDS async 16B copy. LDS dest: wave-uniform base; HW adds lane*16.
typedef __attribute__((address_space(3))) uint32_t lds_u32;
typedef const __attribute__((address_space(1))) uint32_t glb_u32;
static __device__ __forceinline__ void gload16(const void* g, void* lds) {
    __builtin_amdgcn_global_load_lds((glb_u32*)g, (lds_u32*)lds, 16, 0, 0);
}

// ---------------------------------------------------------------------------
// merged combine: 3 weight sets in one launch. grid.x = 3*1024.
// WcT[col][c] = sum_e toX[c][e]*wX[h][e][d] * scl ; col = h*64+d
// ---------------------------------------------------------------------------
__global__ __launch_bounds__(256)
void combine3_k(const float* __restrict__ toQ, const float* __restrict__ wQ, const float* __restrict__ bQ,
                const float* __restrict__ toK, const float* __restrict__ wK, const float* __restrict__ bK,
                const float* __restrict__ toV, const float* __restrict__ wV, const float* __restrict__ bV,
                float sclK,
                u16* __restrict__ WQcT, u16* __restrict__ WKcT, u16* __restrict__ WVcT,
                float* __restrict__ bQc, float* __restrict__ bKc, float* __restrict__ bVc)
{
    const int which = blockIdx.x >> 10;
    const float *toX, *wX, *bX; u16* W; float* bc; float scl;
    if (which == 0)      { toX = toQ; wX = wQ; bX = bQ; W = WQcT; bc = bQc; scl = 1.f; }
    else if (which == 1) { toX = toK; wX = wK; bX = bK; W = WKcT; bc = bKc; scl = sclK; }
    else                 { toX = toV; wX = wV; bX = bV; W = WVcT; bc = bVc; scl = 1.f; }

    const int idx = (blockIdx.x & 1023) * 256 + threadIdx.x;   // 0..262143
    const int col = idx >> 9;          // h*64+d
    const int c   = idx & 511;
    const int h   = col >> 6;
    const int d   = col & 63;
    float acc = 0.f;
    const float* tp = toX + c * 64;
    const float* wp = wX + (h << 12) + d;
    #pragma unroll 8
    for (int e = 0; e < 64; ++e)
        acc += tp[e] * wp[e << 6];
    W[idx] = f2bf(acc * scl);
    if (idx < 512) bc[idx] = bX[idx] * scl;
}

// ---------------------------------------------------------------------------
// merged transpose+cast for wo (512x512), w1 (512x2048), w2 (2048x512).
// grid.x = 256 + 1024 + 1024 = 2304.
// ---------------------------------------------------------------------------
static __device__ __forceinline__ void tcast_body(
    const float* __restrict__ in, u16* __restrict__ out, int R, int Cc, int bid)
{
    __shared__ float t[32][33];
    const int tcx = Cc >> 5;
    const int bx = bid % tcx, by = bid / tcx;
    const int c0 = bx * 32, r0 = by * 32;
    const int tx = threadIdx.x & 31, ty = threadIdx.x >> 5;
    #pragma unroll
    for (int i = 0; i < 4; ++i)
        t[ty + i*8][tx] = in[(size_t)(r0 + ty + i*8) * Cc + c0 + tx];
    __syncthreads();
    #pragma unroll
    for (int i = 0; i < 4; ++i)
        out[(size_t)(c0 + ty + i*8) * R + r0 + tx] = f2bf(t[tx][ty + i*8]);
}

__global__ __launch_bounds__(256)
void tcast3_k(const float* __restrict__ wo, const float* __restrict__ w1,
              const float* __restrict__ w2, u16* __restrict__ woT,
              u16* __restrict__ w1T, u16* __restrict__ w2T)
{
    const int bid = blockIdx.x;
    if (bid < 256)       tcast_body(wo, woT, 512, 512, bid);
    else if (bid < 1280) tcast_body(w1, w1T, 512, 2048, bid - 256);
    else                 tcast_body(w2, w2T, 2048, 512, bid - 1280);
}

// ---------------------------------------------------------------------------
// fp32 -> bf16 cast, 8 elems/thread
// ---------------------------------------------------------------------------
__global__ __launch_bounds__(256)
void castbf_k(const float* __restrict__ in, u16* __restrict__ out)
{
    const size_t i = ((size_t)blockIdx.x * 256 + threadIdx.x) * 8;
    union { u16 h[8]; uint4 u; } pk;
    #pragma unroll
    for (int c = 0; c < 2; ++c) {
        float4 a = *(const float4*)(in + i + c * 4);
        pk.h[c*4+0] = f2bf(a.x); pk.h[c*4+1] = f2bf(a.y);
        pk.h[c*4+2] = f2bf(a.z); pk.h[c*4+3] = f2bf(a.w);
    }
    *(uint4*)(out + i) = pk.u;
}

// ---------------------------------------------------------------------------
// batched bf16 MFMA GEMM: C[M,N] = epi(A[M,K(lda)] @ Bt[N,K(ldb)]^T + bias)
// MODE 0: plain (grid.z=1). MODE 1: A-row eye-gather (m>>8)*2048+(m&255).
// MODE 2: attS slice: z=(b,h). MODE 3: O-gemm batch.
// EPI 0: +bias. 1: +bias,gelu. 2: rcp(64+v), no bias. 3: raw, no bias.
// ---------------------------------------------------------------------------
template<int BM, int BN, int MODE, int EPI, int OUTBF>
__global__ __launch_bounds__(256)
void bgemm_k(const u16* __restrict__ A, const u16* __restrict__ Bt,
             const float* __restrict__ bias, float* __restrict__ Cf,
             u16* __restrict__ Cb, int M, int N, int K,
             int lda, int ldb, int ldc)
{
    constexpr int WM = BM / 2, WN = BN / 2, FM = WM / 16, FN = WN / 16;
    __shared__ __align__(16) u16 As[BM][64];
    __shared__ __align__(16) u16 Bs[BN][64];
    const int z = blockIdx.z;
    if (MODE == 2) {
        A  += ((size_t)(z >> 3)) * (2048u * 512u) + (size_t)(z & 7) * 64u;
        Bt += ((size_t)(z >> 3)) * (256u * 512u)  + (size_t)(z & 7) * 64u;
        Cb += (size_t)z * (2048u * 256u);
    } else if (MODE == 3) {
        A  += (size_t)z * (2048u * 256u);
        Bt += (size_t)z * (128u * 256u);
        Cf += (size_t)z * (2048u * 128u);
    }
    const int tid  = threadIdx.x;
    const int lane = tid & 63, wid = tid >> 6;
    const int wr = wid >> 1, wc = wid & 1;
    const int m0 = blockIdx.y * BM, n0 = blockIdx.x * BN;

    f32x4 acc[FM][FN];
    #pragma unroll
    for (int i = 0; i < FM; ++i)
        #pragma unroll
        for (int j = 0; j < FN; ++j)
            acc[i][j] = (f32x4){0.f, 0.f, 0.f, 0.f};

    u16* ldsA = &As[0][0];
    u16* ldsB = &Bs[0][0];

    for (int k0 = 0; k0 < K; k0 += 64) {
        __syncthreads();
        #pragma unroll
        for (int it = 0; it < BM / 32; ++it) {          // BM*8/256 chunks
            const int f = it * 256 + tid;
            const int row = f >> 3, c8 = f & 7;
            int mrow = m0 + row;
            if (MODE == 1) mrow = (mrow >> 8) * 2048 + (mrow & 255);
            gload16(A + (size_t)mrow * lda + k0 + c8 * 8,
                    ldsA + (it * 256 + wid * 64) * 8);   // wave-uniform dest
        }
        #pragma unroll
        for (int it = 0; it < BN / 32; ++it) {
            const int f = it * 256 + tid;
            const int row = f >> 3, c8 = f & 7;
            gload16(Bt + (size_t)(n0 + row) * ldb + k0 + c8 * 8,
                    ldsB + (it * 256 + wid * 64) * 8);
        }
        __syncthreads();
        #pragma unroll
        for (int kk = 0; kk < 64; kk += 32) {
            bf16x8 af[FM], bfr[FN];
            const int kof  = kk + (lane >> 4) * 8;
            const int rsel = lane & 15;
            #pragma unroll
            for (int m = 0; m < FM; ++m)
                af[m] = *(const bf16x8*)&As[wr * WM + m * 16 + rsel][kof];
            #pragma unroll
            for (int n = 0; n < FN; ++n)
                bfr[n] = *(const bf16x8*)&Bs[wc * WN + n * 16 + rsel][kof];
            #pragma unroll
            for (int m = 0; m < FM; ++m)
                #pragma unroll
                for (int n = 0; n < FN; ++n)
                    acc[m][n] = __builtin_amdgcn_mfma_f32_16x16x32_bf16(
                        af[m], bfr[n], acc[m][n], 0, 0, 0);
        }
    }

    // C/D layout: col = lane&15, row = (lane>>4)*4 + j   [m89 verified]
    const int cl = lane & 15, r4 = (lane >> 4) * 4;
    #pragma unroll
    for (int n = 0; n < FN; ++n) {
        const int col = n0 + wc * WN + n * 16 + cl;
        const float bv = (EPI <= 1) ? bias[col] : 0.f;
        #pragma unroll
        for (int m = 0; m < FM; ++m) {
            #pragma unroll
            for (int j = 0; j < 4; ++j) {
                const int row = m0 + wr * WM + m * 16 + r4 + j;
                float v = acc[m][n][j] + bv;
                if (EPI == 1)
                    v = 0.5f * v * (1.0f + erff(v * 0.70710678118654752f));
                if (EPI == 2)
                    v = __builtin_amdgcn_rcpf(64.0f + v);
                if (OUTBF) Cb[(size_t)row * ldc + col] = f2bf(v);
                else       Cf[(size_t)row * ldc + col] = v;
            }
        }
    }
}

// ---------------------------------------------------------------------------
// vcat: VcatT[bh][d][k] = VW[k][hd];  VcatT[bh][64+d][k] = KW'[k][hd]*VW[k][hd]
// grid (4 kslices, 16 bh), 256 thr. Per block: 128 rows x 64 k -> it<4.
// ---------------------------------------------------------------------------
__global__ __launch_bounds__(256)
void vcat_k(const u16* __restrict__ KWb, const u16* __restrict__ VWb,
            u16* __restrict__ VcatT)
{
    __shared__ float tV[64][65];
    __shared__ float tK[64][65];
    const int ks = blockIdx.x, bh = blockIdx.y;
    const int b = bh >> 3, h = bh & 7;
    const int tid = threadIdx.x;

    #pragma unroll
    for (int it = 0; it < 2; ++it) {
        const int f = it * 256 + tid;
        const int r = f >> 3, c8 = (f & 7) * 8;
        const size_t src = ((size_t)(b * Kz + ks * 64 + r)) * Cz + h * 64 + c8;
        bf16x8 v = *(const bf16x8*)(VWb + src);
        bf16x8 k = *(const bf16x8*)(KWb + src);
        #pragma unroll
        for (int j = 0; j < 8; ++j) {
            tV[r][c8 + j] = bf2f((u16)v[j]);
            tK[r][c8 + j] = bf2f((u16)k[j]);
        }
    }
    __syncthreads();

    #pragma unroll
    for (int it = 0; it < 4; ++it) {
        const int f = it * 256 + tid;          // 0..1023
        const int dcol = f >> 3, k8 = (f & 7) * 8;
        const int d = dcol & 63;
        union { u16 h[8]; uint4 u; } pk;
        #pragma unroll
        for (int j = 0; j < 8; ++j) {
            const float V = tV[k8 + j][d];
            pk.h[j] = f2bf(dcol < 64 ? V : tK[k8 + j][d] * V);
        }
        *(uint4*)(VcatT + ((size_t)bh * 128 + dcol) * 256 + ks * 64 + k8) = pk.u;
    }
}

// ---------------------------------------------------------------------------
// attfin: att[row][hd] = O0[bh][n][d] + q[row][hd] * O1[bh][n][d]; 1024 blocks
// ---------------------------------------------------------------------------
__global__ __launch_bounds__(256)
void attfin_k(const float* __restrict__ O, const u16* __restrict__ Qb,
              u16* __restrict__ attb)
{
    const size_t i8 = (size_t)blockIdx.x * 256 + threadIdx.x;  // 0..262143
    const int row = (int)(i8 >> 6);
    const int hd  = (int)(i8 & 63) * 8;
    const int b = row >> 11, n = row & 2047;
    const int h = hd >> 6, d8 = hd & 63;
    const size_t base = (((size_t)(b * 8 + h) * 2048) + n) * 128 + d8;

    float o0[8], o1[8];
    *(float4*)&o0[0] = *(const float4*)(O + base);
    *(float4*)&o0[4] = *(const float4*)(O + base + 4);
    *(float4*)&o1[0] = *(const float4*)(O + base + 64);
    *(float4*)&o1[4] = *(const float4*)(O + base + 68);
    bf16x8 q = *(const bf16x8*)(Qb + (size_t)row * 512 + hd);

    union { u16 h[8]; uint4 u; } pk;
    #pragma unroll
    for (int j = 0; j < 8; ++j)
        pk.h[j] = f2bf(o0[j] + bf2f((u16)q[j]) * o1[j]);
    *(uint4*)(attb + (size_t)row * 512 + hd) = pk.u;
}

// ---------------------------------------------------------------------------
// fused residual-add + LayerNorm, fp32 out + bf16 out
// ---------------------------------------------------------------------------
__global__ __launch_bounds__(256)
void ln_k(const float* __restrict__ xin, const float* __restrict__ res,
          const float* __restrict__ g, const float* __restrict__ be,
          float* __restrict__ out, u16* __restrict__ outb)
{
    const int tid  = threadIdx.x;
    const int row  = blockIdx.x * 4 + (tid >> 6);
    const int lane = tid & 63;
    const size_t base = (size_t)row * 512 + lane * 8;

    float v[8];
    float s1 = 0.f, s2 = 0.f;
    #pragma unroll
    for (int c = 0; c < 2; ++c) {
        float4 a = *(const float4*)(xin + base + c * 4);
        float4 b = *(const float4*)(res + base + c * 4);
        float t0 = a.x + b.x, t1 = a.y + b.y, t2 = a.z + b.z, t3 = a.w + b.w;
        v[c*4+0] = t0; v[c*4+1] = t1; v[c*4+2] = t2; v[c*4+3] = t3;
        s1 += (t0 + t1) + (t2 + t3);
        s2 += (t0*t0 + t1*t1) + (t2*t2 + t3*t3);
    }
    #pragma unroll
    for (int off = 32; off >= 1; off >>= 1) {
        s1 += __shfl_xor(s1, off, 64);
        s2 += __shfl_xor(s2, off, 64);
    }
    const float mean = s1 * (1.f / 512.f);
    const float var  = s2 * (1.f / 512.f) - mean * mean;
    const float rs   = __builtin_amdgcn_rsqf(var + 1e-5f);

    union { u16 h[8]; uint4 u; } pk;
    #pragma unroll
    for (int c = 0; c < 2; ++c) {
        float4 gg = *(const float4*)(g  + lane * 8 + c * 4);
        float4 bb = *(const float4*)(be + lane * 8 + c * 4);
        float4 t;
        t.x = (v[c*4+0] - mean) * rs * gg.x + bb.x;
        t.y = (v[c*4+1] - mean) * rs * gg.y + bb.y;
        t.z = (v[c*4+2] - mean) * rs * gg.z + bb.z;
        t.w = (v[c*4+3] - mean) * rs * gg.w + bb.w;
        *(float4*)(out + base + c * 4) = t;
        pk.h[c*4+0] = f2bf(t.x); pk.h[c*4+1] = f2bf(t.y);
        pk.h[c*4+2] = f2bf(t.z); pk.h[c*4+3] = f2bf(t.w);
    }
    *(uint4*)(outb + base) = pk.u;
}

// ---------------------------------------------------------------------------
extern "C" void kernel_launch(void* const* d_in, const int* in_sizes, int n_in,
                              void* d_out, int out_size, void* d_ws, size_t ws_size,
                              hipStream_t stream)
{
    const float* xin  = (const float*)d_in[0];
    const float* to_q = (const float*)d_in[1];
    const float* to_k = (const float*)d_in[2];
    const float* to_v = (const float*)d_in[3];
    const float* wq   = (const float*)d_in[4];
    const float* bq   = (const float*)d_in[5];
    const float* wk   = (const float*)d_in[6];
    const float* bk   = (const float*)d_in[7];
    const float* wv   = (const float*)d_in[8];
    const float* bv   = (const float*)d_in[9];
    const float* wo   = (const float*)d_in[10];
    const float* bo   = (const float*)d_in[11];
    const float* g1   = (const float*)d_in[12];
    const float* be1  = (const float*)d_in[13];
    const float* w1   = (const float*)d_in[14];
    const float* bb1  = (const float*)d_in[15];
    const float* w2   = (const float*)d_in[16];
    const float* bb2  = (const float*)d_in[17];
    const float* g2   = (const float*)d_in[18];
    const float* be2  = (const float*)d_in[19];
    (void)in_sizes; (void)n_in; (void)out_size; (void)ws_size;

    float* p = (float*)d_ws;
    float* xcur = p;  p += XELEMS;
    float* xmid = p;  p += XELEMS;
    float* obuf = p;  p += 2 * (size_t)XELEMS;     // fp32; also O scratch [16][2048][128]
    u16*  QWb16 = (u16*)p;  p += XELEMS / 2;
    u16*  KWb16 = (u16*)p;  p += (Bz * Kz * Cz) / 2;
    u16*  VWb16 = (u16*)p;  p += (Bz * Kz * Cz) / 2;
    u16*  hb    = (u16*)p;  p += XELEMS * 2;       // ffn hidden bf16; aliases Rb
    u16*  Rb    = hb;                              // [16][2048][256] bf16 (disjoint liveness)
    u16*  VcatT = (u16*)p;  p += (Bz * Hz * 128 * 256) / 2;
    u16*  attb  = (u16*)p;  p += XELEMS / 2;
    u16*  xb    = (u16*)p;  p += XELEMS / 2;
    u16*  xmidb = (u16*)p;  p += XELEMS / 2;
    u16*  WQcT  = (u16*)p;  p += (Cz * Cz) / 2;
    u16*  WKcT  = (u16*)p;  p += (Cz * Cz) / 2;
    u16*  WVcT  = (u16*)p;  p += (Cz * Cz) / 2;
    u16*  woT   = (u16*)p;  p += (Cz * Cz) / 2;
    u16*  w1T   = (u16*)p;  p += (Cz * FFz) / 2;
    u16*  w2T   = (u16*)p;  p += (Cz * FFz) / 2;
    float* bQc  = p;  p += Cz;
    float* bKc  = p;  p += Cz;
    float* bVc  = p;  p += Cz;
    float* Obuf = obuf;   // [16][2048][128] fp32 = 2*XELEMS exactly

    const float sK = 0.125f;   // 1/sqrt(D) folded into KW'

    for (int l = 0; l < Lz; ++l) {
        const float* xl   = (l == 0) ? xin : xcur;
        float*       xout = (l == Lz - 1) ? (float*)d_out : xcur;

        combine3_k<<<3072, 256, 0, stream>>>(
            to_q + l*32768, wq + l*32768, bq + l*512,
            to_k + l*32768, wk + l*32768, bk + l*512,
            to_v + l*32768, wv + l*32768, bv + l*512, sK,
            WQcT, WKcT, WVcT, bQc, bKc, bVc);
        tcast3_k<<<2304, 256, 0, stream>>>(wo + l*262144, w1 + l*1048576,
                                           w2 + l*1048576, woT, w1T, w2T);
        if (l == 0) castbf_k<<<1024, 256, 0, stream>>>(xin, xb);

        // QKV projections -> bf16 (K/V: eye-slice gather, M=512)
        bgemm_k<128,64,0,0,1><<<dim3(8,32,1), 256, 0, stream>>>(xb, WQcT, bQc, nullptr, QWb16, 4096, 512, 512, 512, 512, 512);
        bgemm_k<64,64,1,0,1><<<dim3(8,8,1),   256, 0, stream>>>(xb, WKcT, bKc, nullptr, KWb16, 512,  512, 512, 512, 512, 512);
        bgemm_k<64,64,1,0,1><<<dim3(8,8,1),   256, 0, stream>>>(xb, WVcT, bVc, nullptr, VWb16, 512,  512, 512, 512, 512, 512);

        // Taylor-1 channel-softmax attention:
        //   R = 1/(64 + QW_h @ KW'_h^T);  out = R@V + q  (R@(KW'.V))
        vcat_k<<<dim3(4,16), 256, 0, stream>>>(KWb16, VWb16, VcatT);
        bgemm_k<64,64,2,2,1><<<dim3(4,32,16), 256, 0, stream>>>(QWb16, KWb16, nullptr, nullptr, Rb, 2048, 256, 64, 512, 512, 256);
        bgemm_k<64,64,3,3,0><<<dim3(2,32,16), 256, 0, stream>>>(Rb, VcatT, nullptr, Obuf, nullptr, 2048, 128, 256, 256, 256, 128);
        attfin_k<<<1024, 256, 0, stream>>>(Obuf, QWb16, attb);

        bgemm_k<128,64,0,0,0><<<dim3(8,32,1), 256, 0, stream>>>(attb, woT, bo + l*512, obuf, nullptr, 4096, 512, 512, 512, 512, 512);
        ln_k<<<1024, 256, 0, stream>>>(obuf, xl, g1 + l*512, be1 + l*512, xmid, xmidb);

        bgemm_k<128,128,0,1,1><<<dim3(16,32,1), 256, 0, stream>>>(xmidb, w1T, bb1 + l*2048, nullptr, hb, 4096, 2048, 512, 512, 512, 2048);
        bgemm_k<128,64,0,0,0><<<dim3(8,32,1),   256, 0, stream>>>(hb, w2T, bb2 + l*512, obuf, nullptr, 4096, 512, 2048, 2048, 2048, 512);
        ln_k<<<1024, 256, 0, stream>>>(obuf, xmid, g2 + l*512, be2 + l*512, xout, xb);
    }
}

// Round 14
// 399.965 us; speedup vs baseline: 1.1066x; 1.1066x over previous
//
#include <hip/hip_runtime.h>
#include <hip/hip_bf16.h>
#include <stdint.h>

#define Bz 2
#define Nz 2048
#define Cz 512
#define Hz 8
#define Kz 256
#define Lz 2
#define Dz 64
#define FFz 2048
#define BN_ROWS (Bz*Nz)          // 4096
#define XELEMS  (BN_ROWS*Cz)     // 2097152

typedef __attribute__((ext_vector_type(8))) short bf16x8;
typedef __attribute__((ext_vector_type(4))) float f32x4;
typedef unsigned short u16;

static __device__ __forceinline__ u16 f2bf(float f) {
    union { float f; uint32_t u; } v; v.f = f;
    return (u16)((v.u + 0x7FFFu + ((v.u >> 16) & 1u)) >> 16);
}
static __device__ __forceinline__ float bf2f(u16 h) {
    union { uint32_t u; float f; } v; v.u = ((uint32_t)h) << 16;
    return v.f;
}

// global -> LDS async 16B copy. LDS dest: wave-uniform base; HW adds lane*16.
typedef __attribute__((address_space(3))) uint32_t lds_u32;
typedef const __attribute__((address_space(1))) uint32_t glb_u32;
static __device__ __forceinline__ void gload16(const void* g, void* lds) {
    __builtin_amdgcn_global_load_lds((glb_u32*)g, (lds_u32*)lds, 16, 0, 0);
}

// ---------------------------------------------------------------------------
// combine3 (BOTH layers): grid.x = 6*1024. sel = blk>>10: l = sel/3, which = sel%3.
// WQcT[l][col][c]; WKVcT[l][row][c] rows 0..511 = K' (scaled), 512..1023 = V.
// ---------------------------------------------------------------------------
__global__ __launch_bounds__(256)
void combine3_k(const float* __restrict__ toQ, const float* __restrict__ wQ, const float* __restrict__ bQ,
                const float* __restrict__ toK, const float* __restrict__ wK, const float* __restrict__ bK,
                const float* __restrict__ toV, const float* __restrict__ wV, const float* __restrict__ bV,
                float sclK,
                u16* __restrict__ WQcT, u16* __restrict__ WKVcT,
                float* __restrict__ bQc, float* __restrict__ bKVc)
{
    const int sel = blockIdx.x >> 10;      // 0..5
    const int l = sel / 3, which = sel % 3;
    const float *toX, *wX, *bX; u16* W; float* bc; float scl;
    if (which == 0)      { toX = toQ + l*32768; wX = wQ + l*32768; bX = bQ + l*512;
                           W = WQcT + l*262144;           bc = bQc + l*512;         scl = 1.f; }
    else if (which == 1) { toX = toK + l*32768; wX = wK + l*32768; bX = bK + l*512;
                           W = WKVcT + l*524288;          bc = bKVc + l*1024;       scl = sclK; }
    else                 { toX = toV + l*32768; wX = wV + l*32768; bX = bV + l*512;
                           W = WKVcT + l*524288 + 262144; bc = bKVc + l*1024 + 512; scl = 1.f; }

    const int idx = (blockIdx.x & 1023) * 256 + threadIdx.x;   // 0..262143
    const int col = idx >> 9;          // h*64+d
    const int c   = idx & 511;
    const int h   = col >> 6;
    const int d   = col & 63;
    float acc = 0.f;
    const float* tp = toX + c * 64;
    const float* wp = wX + (h << 12) + d;
    #pragma unroll 8
    for (int e = 0; e < 64; ++e)
        acc += tp[e] * wp[e << 6];
    W[idx] = f2bf(acc * scl);
    if (idx < 512) bc[idx] = bX[idx] * scl;
}

// ---------------------------------------------------------------------------
// tcast3 (BOTH layers): grid.x = 2*2304.
// ---------------------------------------------------------------------------
static __device__ __forceinline__ void tcast_body(
    const float* __restrict__ in, u16* __restrict__ out, int R, int Cc, int bid)
{
    __shared__ float t[32][33];
    const int tcx = Cc >> 5;
    const int bx = bid % tcx, by = bid / tcx;
    const int c0 = bx * 32, r0 = by * 32;
    const int tx = threadIdx.x & 31, ty = threadIdx.x >> 5;
    #pragma unroll
    for (int i = 0; i < 4; ++i)
        t[ty + i*8][tx] = in[(size_t)(r0 + ty + i*8) * Cc + c0 + tx];
    __syncthreads();
    #pragma unroll
    for (int i = 0; i < 4; ++i)
        out[(size_t)(c0 + ty + i*8) * R + r0 + tx] = f2bf(t[tx][ty + i*8]);
}

__global__ __launch_bounds__(256)
void tcast3_k(const float* __restrict__ wo, const float* __restrict__ w1,
              const float* __restrict__ w2, u16* __restrict__ woT,
              u16* __restrict__ w1T, u16* __restrict__ w2T)
{
    const int l = blockIdx.x / 2304;
    const int bid = blockIdx.x % 2304;
    if (bid < 256)       tcast_body(wo + l*262144,  woT + l*262144,  512, 512,  bid);
    else if (bid < 1280) tcast_body(w1 + l*1048576, w1T + l*1048576, 512, 2048, bid - 256);
    else                 tcast_body(w2 + l*1048576, w2T + l*1048576, 2048, 512, bid - 1280);
}

// ---------------------------------------------------------------------------
// fp32 -> bf16 cast, 8 elems/thread
// ---------------------------------------------------------------------------
__global__ __launch_bounds__(256)
void castbf_k(const float* __restrict__ in, u16* __restrict__ out)
{
    const size_t i = ((size_t)blockIdx.x * 256 + threadIdx.x) * 8;
    union { u16 h[8]; uint4 u; } pk;
    #pragma unroll
    for (int c = 0; c < 2; ++c) {
        float4 a = *(const float4*)(in + i + c * 4);
        pk.h[c*4+0] = f2bf(a.x); pk.h[c*4+1] = f2bf(a.y);
        pk.h[c*4+2] = f2bf(a.z); pk.h[c*4+3] = f2bf(a.w);
    }
    *(uint4*)(out + i) = pk.u;
}

// ---------------------------------------------------------------------------
// batched bf16 MFMA GEMM: C[M,N] = epi(A[M,K(lda)] @ Bt[N,K(ldb)]^T + bias)
// MODE 0: plain. MODE 1: A-row eye-gather (m>>8)*2048+(m&255).
// MODE 2: R-gemm slice z=(b,h): A+=(z>>3)*2048*512+(z&7)*64,
//         Bt+=(z>>3)*256*1024+(z&7)*64 (merged KWVb, ldb=1024), Cb+=z*2048*256.
// MODE 4: O-gemm batch: A+=z*2048*256 (Rb), Bt+=z*128*256 (VcatT interleaved).
// EPI 0: +bias. 1: +bias,gelu. 2: rcp(64+v). 4: fused attfin via shfl_xor(1):
//        col c=2d+s; att[row][h*64+d] = o0 + q*o1, bf16 into Cb (attb).
// ---------------------------------------------------------------------------
template<int BM, int BN, int MODE, int EPI, int OUTBF>
__global__ __launch_bounds__(256)
void bgemm_k(const u16* __restrict__ A, const u16* __restrict__ Bt,
             const float* __restrict__ bias, float* __restrict__ Cf,
             u16* __restrict__ Cb, int M, int N, int K,
             int lda, int ldb, int ldc, const u16* __restrict__ Qb)
{
    constexpr int WM = BM / 2, WN = BN / 2, FM = WM / 16, FN = WN / 16;
    __shared__ __align__(16) u16 As[BM][64];
    __shared__ __align__(16) u16 Bs[BN][64];
    const int z = blockIdx.z;
    if (MODE == 2) {
        A  += ((size_t)(z >> 3)) * (2048u * 512u)  + (size_t)(z & 7) * 64u;
        Bt += ((size_t)(z >> 3)) * (256u * 1024u)  + (size_t)(z & 7) * 64u;
        Cb += (size_t)z * (2048u * 256u);
    } else if (MODE == 4) {
        A  += (size_t)z * (2048u * 256u);
        Bt += (size_t)z * (128u * 256u);
    }
    const int tid  = threadIdx.x;
    const int lane = tid & 63, wid = tid >> 6;
    const int wr = wid >> 1, wc = wid & 1;
    const int m0 = blockIdx.y * BM, n0 = blockIdx.x * BN;

    f32x4 acc[FM][FN];
    #pragma unroll
    for (int i = 0; i < FM; ++i)
        #pragma unroll
        for (int j = 0; j < FN; ++j)
            acc[i][j] = (f32x4){0.f, 0.f, 0.f, 0.f};

    u16* ldsA = &As[0][0];
    u16* ldsB = &Bs[0][0];

    for (int k0 = 0; k0 < K; k0 += 64) {
        __syncthreads();
        #pragma unroll
        for (int it = 0; it < BM / 32; ++it) {          // BM*8/256 chunks
            const int f = it * 256 + tid;
            const int row = f >> 3, c8 = f & 7;
            int mrow = m0 + row;
            if (MODE == 1) mrow = (mrow >> 8) * 2048 + (mrow & 255);
            gload16(A + (size_t)mrow * lda + k0 + c8 * 8,
                    ldsA + (it * 256 + wid * 64) * 8);   // wave-uniform dest
        }
        #pragma unroll
        for (int it = 0; it < BN / 32; ++it) {
            const int f = it * 256 + tid;
            const int row = f >> 3, c8 = f & 7;
            gload16(Bt + (size_t)(n0 + row) * ldb + k0 + c8 * 8,
                    ldsB + (it * 256 + wid * 64) * 8);
        }
        __syncthreads();
        #pragma unroll
        for (int kk = 0; kk < 64; kk += 32) {
            bf16x8 af[FM], bfr[FN];
            const int kof  = kk + (lane >> 4) * 8;
            const int rsel = lane & 15;
            #pragma unroll
            for (int m = 0; m < FM; ++m)
                af[m] = *(const bf16x8*)&As[wr * WM + m * 16 + rsel][kof];
            #pragma unroll
            for (int n = 0; n < FN; ++n)
                bfr[n] = *(const bf16x8*)&Bs[wc * WN + n * 16 + rsel][kof];
            #pragma unroll
            for (int m = 0; m < FM; ++m)
                #pragma unroll
                for (int n = 0; n < FN; ++n)
                    acc[m][n] = __builtin_amdgcn_mfma_f32_16x16x32_bf16(
                        af[m], bfr[n], acc[m][n], 0, 0, 0);
        }
    }

    // C/D layout: col = lane&15, row = (lane>>4)*4 + j   [m89 verified]
    const int cl = lane & 15, r4 = (lane >> 4) * 4;

    if (EPI == 4) {
        // fused attfin: c = wc*WN + n*16 + cl = 2d+s; lanes cl, cl^1 hold (o0,o1)
        const int b = z >> 3, h = z & 7;
        #pragma unroll
        for (int n = 0; n < FN; ++n) {
            const int c = wc * WN + n * 16 + cl;
            const int d = c >> 1;
            #pragma unroll
            for (int m = 0; m < FM; ++m) {
                #pragma unroll
                for (int j = 0; j < 4; ++j) {
                    const int row = m0 + wr * WM + m * 16 + r4 + j;
                    const size_t gidx = ((size_t)(b * 2048 + row)) * 512 + h * 64 + d;
                    float o = acc[m][n][j];
                    float po = __shfl_xor(o, 1, 64);
                    if ((cl & 1) == 0)
                        Cb[gidx] = f2bf(o + bf2f(Qb[gidx]) * po);
                }
            }
        }
        return;
    }

    #pragma unroll
    for (int n = 0; n < FN; ++n) {
        const int col = n0 + wc * WN + n * 16 + cl;
        const float bv = (EPI <= 1) ? bias[col] : 0.f;
        #pragma unroll
        for (int m = 0; m < FM; ++m) {
            #pragma unroll
            for (int j = 0; j < 4; ++j) {
                const int row = m0 + wr * WM + m * 16 + r4 + j;
                float v = acc[m][n][j] + bv;
                if (EPI == 1)
                    v = 0.5f * v * (1.0f + erff(v * 0.70710678118654752f));
                if (EPI == 2)
                    v = __builtin_amdgcn_rcpf(64.0f + v);
                if (OUTBF) Cb[(size_t)row * ldc + col] = f2bf(v);
                else       Cf[(size_t)row * ldc + col] = v;
            }
        }
    }
}

// ---------------------------------------------------------------------------
// vcat (interleaved): VcatT[bh][2d+0][k] = V;  VcatT[bh][2d+1][k] = K'*V.
// Reads merged KWVb [512][1024]: cols 0..511 = K', 512..1023 = V.
// grid (4 kslices, 16 bh). Per block: 128 dcol x 64 k -> it<4.
// ---------------------------------------------------------------------------
__global__ __launch_bounds__(256)
void vcat_k(const u16* __restrict__ KWVb, u16* __restrict__ VcatT)
{
    __shared__ float tV[64][65];
    __shared__ float tK[64][65];
    const int ks = blockIdx.x, bh = blockIdx.y;
    const int b = bh >> 3, h = bh & 7;
    const int tid = threadIdx.x;

    #pragma unroll
    for (int it = 0; it < 2; ++it) {
        const int f = it * 256 + tid;
        const int r = f >> 3, c8 = (f & 7) * 8;
        const size_t src = ((size_t)(b * Kz + ks * 64 + r)) * 1024 + h * 64 + c8;
        bf16x8 k = *(const bf16x8*)(KWVb + src);
        bf16x8 v = *(const bf16x8*)(KWVb + src + 512);
        #pragma unroll
        for (int j = 0; j < 8; ++j) {
            tK[r][c8 + j] = bf2f((u16)k[j]);
            tV[r][c8 + j] = bf2f((u16)v[j]);
        }
    }
    __syncthreads();

    #pragma unroll
    for (int it = 0; it < 4; ++it) {
        const int f = it * 256 + tid;          // 0..1023
        const int dcol = f >> 3, k8 = (f & 7) * 8;
        const int d = dcol >> 1, s = dcol & 1;
        union { u16 h[8]; uint4 u; } pk;
        #pragma unroll
        for (int j = 0; j < 8; ++j) {
            const float V = tV[k8 + j][d];
            pk.h[j] = f2bf(s ? tK[k8 + j][d] * V : V);
        }
        *(uint4*)(VcatT + ((size_t)bh * 128 + dcol) * 256 + ks * 64 + k8) = pk.u;
    }
}

// ---------------------------------------------------------------------------
// fused residual-add + LayerNorm, fp32 out + bf16 out
// ---------------------------------------------------------------------------
__global__ __launch_bounds__(256)
void ln_k(const float* __restrict__ xin, const float* __restrict__ res,
          const float* __restrict__ g, const float* __restrict__ be,
          float* __restrict__ out, u16* __restrict__ outb)
{
    const int tid  = threadIdx.x;
    const int row  = blockIdx.x * 4 + (tid >> 6);
    const int lane = tid & 63;
    const size_t base = (size_t)row * 512 + lane * 8;

    float v[8];
    float s1 = 0.f, s2 = 0.f;
    #pragma unroll
    for (int c = 0; c < 2; ++c) {
        float4 a = *(const float4*)(xin + base + c * 4);
        float4 b = *(const float4*)(res + base + c * 4);
        float t0 = a.x + b.x, t1 = a.y + b.y, t2 = a.z + b.z, t3 = a.w + b.w;
        v[c*4+0] = t0; v[c*4+1] = t1; v[c*4+2] = t2; v[c*4+3] = t3;
        s1 += (t0 + t1) + (t2 + t3);
        s2 += (t0*t0 + t1*t1) + (t2*t2 + t3*t3);
    }
    #pragma unroll
    for (int off = 32; off >= 1; off >>= 1) {
        s1 += __shfl_xor(s1, off, 64);
        s2 += __shfl_xor(s2, off, 64);
    }
    const float mean = s1 * (1.f / 512.f);
    const float var  = s2 * (1.f / 512.f) - mean * mean;
    const float rs   = __builtin_amdgcn_rsqf(var + 1e-5f);

    union { u16 h[8]; uint4 u; } pk;
    #pragma unroll
    for (int c = 0; c < 2; ++c) {
        float4 gg = *(const float4*)(g  + lane * 8 + c * 4);
        float4 bb = *(const float4*)(be + lane * 8 + c * 4);
        float4 t;
        t.x = (v[c*4+0] - mean) * rs * gg.x + bb.x;
        t.y = (v[c*4+1] - mean) * rs * gg.y + bb.y;
        t.z = (v[c*4+2] - mean) * rs * gg.z + bb.z;
        t.w = (v[c*4+3] - mean) * rs * gg.w + bb.w;
        *(float4*)(out + base + c * 4) = t;
        pk.h[c*4+0] = f2bf(t.x); pk.h[c*4+1] = f2bf(t.y);
        pk.h[c*4+2] = f2bf(t.z); pk.h[c*4+3] = f2bf(t.w);
    }
    *(uint4*)(outb + base) = pk.u;
}

// ---------------------------------------------------------------------------
extern "C" void kernel_launch(void* const* d_in, const int* in_sizes, int n_in,
                              void* d_out, int out_size, void* d_ws, size_t ws_size,
                              hipStream_t stream)
{
    const float* xin  = (const float*)d_in[0];
    const float* to_q = (const float*)d_in[1];
    const float* to_k = (const float*)d_in[2];
    const float* to_v = (const float*)d_in[3];
    const float* wq   = (const float*)d_in[4];
    const float* bq   = (const float*)d_in[5];
    const float* wk   = (const float*)d_in[6];
    const float* bk   = (const float*)d_in[7];
    const float* wv   = (const float*)d_in[8];
    const float* bv   = (const float*)d_in[9];
    const float* wo   = (const float*)d_in[10];
    const float* bo   = (const float*)d_in[11];
    const float* g1   = (const float*)d_in[12];
    const float* be1  = (const float*)d_in[13];
    const float* w1   = (const float*)d_in[14];
    const float* bb1  = (const float*)d_in[15];
    const float* w2   = (const float*)d_in[16];
    const float* bb2  = (const float*)d_in[17];
    const float* g2   = (const float*)d_in[18];
    const float* be2  = (const float*)d_in[19];
    (void)in_sizes; (void)n_in; (void)out_size; (void)ws_size;

    float* p = (float*)d_ws;
    float* xcur = p;  p += XELEMS;
    float* xmid = p;  p += XELEMS;
    float* obuf = p;  p += XELEMS;                 // fp32 GEMM out (wo / ffn2)
    u16*  QWb16 = (u16*)p;  p += XELEMS / 2;
    u16*  KWVb  = (u16*)p;  p += (512 * 1024) / 2; // [512][1024]: K' | V
    u16*  hb    = (u16*)p;  p += XELEMS * 2;       // ffn hidden bf16; aliases Rb
    u16*  Rb    = hb;                              // [16][2048][256] bf16
    u16*  VcatT = (u16*)p;  p += (Bz * Hz * 128 * 256) / 2;  // interleaved
    u16*  attb  = (u16*)p;  p += XELEMS / 2;
    u16*  xb    = (u16*)p;  p += XELEMS / 2;
    u16*  xmidb = (u16*)p;  p += XELEMS / 2;
    u16*  WQcT  = (u16*)p;  p += (2 * Cz * Cz) / 2;        // per-layer
    u16*  WKVcT = (u16*)p;  p += (2 * Cz * 2 * Cz) / 2;    // per-layer [1024][512]
    u16*  woT   = (u16*)p;  p += (2 * Cz * Cz) / 2;
    u16*  w1T   = (u16*)p;  p += (2 * Cz * FFz) / 2;
    u16*  w2T   = (u16*)p;  p += (2 * Cz * FFz) / 2;
    float* bQc  = p;  p += 2 * Cz;
    float* bKVc = p;  p += 2 * 1024;

    const float sK = 0.125f;   // 1/sqrt(D) folded into K'

    // weight prep for BOTH layers, once
    combine3_k<<<6144, 256, 0, stream>>>(to_q, wq, bq, to_k, wk, bk, to_v, wv, bv,
                                         sK, WQcT, WKVcT, bQc, bKVc);
    tcast3_k<<<4608, 256, 0, stream>>>(wo, w1, w2, woT, w1T, w2T);
    castbf_k<<<1024, 256, 0, stream>>>(xin, xb);

    for (int l = 0; l < Lz; ++l) {
        const float* xl   = (l == 0) ? xin : xcur;
        float*       xout = (l == Lz - 1) ? (float*)d_out : xcur;

        // Q projection (M=4096) and merged K|V projection (M=512 gather, N=1024)
        bgemm_k<64,64,0,0,1><<<dim3(8,64,1), 256, 0, stream>>>(
            xb, WQcT + l*262144, bQc + l*512, nullptr, QWb16,
            4096, 512, 512, 512, 512, 512, nullptr);
        bgemm_k<64,64,1,0,1><<<dim3(16,8,1), 256, 0, stream>>>(
            xb, WKVcT + l*524288, bKVc + l*1024, nullptr, KWVb,
            512, 1024, 512, 512, 512, 1024, nullptr);

        // Taylor-1 channel-softmax attention:
        //   R = 1/(64 + QW @ K'^T);  att = R@V + q .* (R@(K'.V))  [fused epilogue]
        vcat_k<<<dim3(4,16), 256, 0, stream>>>(KWVb, VcatT);
        bgemm_k<64,64,2,2,1><<<dim3(4,32,16), 256, 0, stream>>>(
            QWb16, KWVb, nullptr, nullptr, Rb,
            2048, 256, 64, 512, 1024, 256, nullptr);
        bgemm_k<64,128,4,4,1><<<dim3(1,32,16), 256, 0, stream>>>(
            Rb, VcatT, nullptr, nullptr, attb,
            2048, 128, 256, 256, 256, 512, QWb16);

        bgemm_k<64,64,0,0,0><<<dim3(8,64,1), 256, 0, stream>>>(
            attb, woT + l*262144, bo + l*512, obuf, nullptr,
            4096, 512, 512, 512, 512, 512, nullptr);
        ln_k<<<1024, 256, 0, stream>>>(obuf, xl, g1 + l*512, be1 + l*512, xmid, xmidb);

        bgemm_k<128,128,0,1,1><<<dim3(16,32,1), 256, 0, stream>>>(
            xmidb, w1T + l*1048576, bb1 + l*2048, nullptr, hb,
            4096, 2048, 512, 512, 512, 2048, nullptr);
        bgemm_k<64,64,0,0,0><<<dim3(8,64,1), 256, 0, stream>>>(
            hb, w2T + l*1048576, bb2 + l*512, obuf, nullptr,
            4096, 512, 2048, 2048, 2048, 512, nullptr);
        ln_k<<<1024, 256, 0, stream>>>(obuf, xmid, g2 + l*512, be2 + l*512, xout, xb);
    }
}

// Round 15
// 397.486 us; speedup vs baseline: 1.1135x; 1.0062x over previous
//
#include <hip/hip_runtime.h>
#include <hip/hip_bf16.h>
#include <stdint.h>

#define Bz 2
#define Nz 2048
#define Cz 512
#define Hz 8
#define Kz 256
#define Lz 2
#define Dz 64
#define FFz 2048
#define BN_ROWS (Bz*Nz)          // 4096
#define XELEMS  (BN_ROWS*Cz)     // 2097152

typedef __attribute__((ext_vector_type(8))) short bf16x8;
typedef __attribute__((ext_vector_type(4))) float f32x4;
typedef unsigned short u16;

static __device__ __forceinline__ u16 f2bf(float f) {
    union { float f; uint32_t u; } v; v.f = f;
    return (u16)((v.u + 0x7FFFu + ((v.u >> 16) & 1u)) >> 16);
}
static __device__ __forceinline__ float bf2f(u16 h) {
    union { uint32_t u; float f; } v; v.u = ((uint32_t)h) << 16;
    return v.f;
}

// global -> LDS async 16B copy. LDS dest: wave-uniform base; HW adds lane*16.
typedef __attribute__((address_space(3))) uint32_t lds_u32;
typedef const __attribute__((address_space(1))) uint32_t glb_u32;
static __device__ __forceinline__ void gload16(const void* g, void* lds) {
    __builtin_amdgcn_global_load_lds((glb_u32*)g, (lds_u32*)lds, 16, 0, 0);
}

// ---------------------------------------------------------------------------
// combine3 (BOTH layers): grid.x = 6*1024. sel = blk>>10: l = sel/3, which = sel%3.
// WQcT[l][col][c]; WKVcT[l][row][c] rows 0..511 = K' (scaled), 512..1023 = V.
// float4 tp loads + 4 accumulators: 16 independent 16B loads in flight (ILP).
// ---------------------------------------------------------------------------
__global__ __launch_bounds__(256)
void combine3_k(const float* __restrict__ toQ, const float* __restrict__ wQ, const float* __restrict__ bQ,
                const float* __restrict__ toK, const float* __restrict__ wK, const float* __restrict__ bK,
                const float* __restrict__ toV, const float* __restrict__ wV, const float* __restrict__ bV,
                float sclK,
                u16* __restrict__ WQcT, u16* __restrict__ WKVcT,
                float* __restrict__ bQc, float* __restrict__ bKVc)
{
    const int sel = blockIdx.x >> 10;      // 0..5
    const int l = sel / 3, which = sel % 3;
    const float *toX, *wX, *bX; u16* W; float* bc; float scl;
    if (which == 0)      { toX = toQ + l*32768; wX = wQ + l*32768; bX = bQ + l*512;
                           W = WQcT + l*262144;           bc = bQc + l*512;         scl = 1.f; }
    else if (which == 1) { toX = toK + l*32768; wX = wK + l*32768; bX = bK + l*512;
                           W = WKVcT + l*524288;          bc = bKVc + l*1024;       scl = sclK; }
    else                 { toX = toV + l*32768; wX = wV + l*32768; bX = bV + l*512;
                           W = WKVcT + l*524288 + 262144; bc = bKVc + l*1024 + 512; scl = 1.f; }

    const int idx = (blockIdx.x & 1023) * 256 + threadIdx.x;   // 0..262143
    const int col = idx >> 9;          // h*64+d
    const int c   = idx & 511;
    const int h   = col >> 6;
    const int d   = col & 63;
    const float4* tp4 = (const float4*)(toX + c * 64);
    const float*  wp  = wX + (h << 12) + d;
    float a0 = 0.f, a1 = 0.f, a2 = 0.f, a3 = 0.f;
    #pragma unroll
    for (int e4 = 0; e4 < 16; ++e4) {
        float4 t = tp4[e4];
        a0 += t.x * wp[(e4 * 4 + 0) << 6];
        a1 += t.y * wp[(e4 * 4 + 1) << 6];
        a2 += t.z * wp[(e4 * 4 + 2) << 6];
        a3 += t.w * wp[(e4 * 4 + 3) << 6];
    }
    W[idx] = f2bf(((a0 + a1) + (a2 + a3)) * scl);
    if (idx < 512) bc[idx] = bX[idx] * scl;
}

// ---------------------------------------------------------------------------
// tcast3 (BOTH layers): grid.x = 2*2304.
// ---------------------------------------------------------------------------
static __device__ __forceinline__ void tcast_body(
    const float* __restrict__ in, u16* __restrict__ out, int R, int Cc, int bid)
{
    __shared__ float t[32][33];
    const int tcx = Cc >> 5;
    const int bx = bid % tcx, by = bid / tcx;
    const int c0 = bx * 32, r0 = by * 32;
    const int tx = threadIdx.x & 31, ty = threadIdx.x >> 5;
    #pragma unroll
    for (int i = 0; i < 4; ++i)
        t[ty + i*8][tx] = in[(size_t)(r0 + ty + i*8) * Cc + c0 + tx];
    __syncthreads();
    #pragma unroll
    for (int i = 0; i < 4; ++i)
        out[(size_t)(c0 + ty + i*8) * R + r0 + tx] = f2bf(t[tx][ty + i*8]);
}

__global__ __launch_bounds__(256)
void tcast3_k(const float* __restrict__ wo, const float* __restrict__ w1,
              const float* __restrict__ w2, u16* __restrict__ woT,
              u16* __restrict__ w1T, u16* __restrict__ w2T)
{
    const int l = blockIdx.x / 2304;
    const int bid = blockIdx.x % 2304;
    if (bid < 256)       tcast_body(wo + l*262144,  woT + l*262144,  512, 512,  bid);
    else if (bid < 1280) tcast_body(w1 + l*1048576, w1T + l*1048576, 512, 2048, bid - 256);
    else                 tcast_body(w2 + l*1048576, w2T + l*1048576, 2048, 512, bid - 1280);
}

// ---------------------------------------------------------------------------
// fp32 -> bf16 cast, 8 elems/thread
// ---------------------------------------------------------------------------
__global__ __launch_bounds__(256)
void castbf_k(const float* __restrict__ in, u16* __restrict__ out)
{
    const size_t i = ((size_t)blockIdx.x * 256 + threadIdx.x) * 8;
    union { u16 h[8]; uint4 u; } pk;
    #pragma unroll
    for (int c = 0; c < 2; ++c) {
        float4 a = *(const float4*)(in + i + c * 4);
        pk.h[c*4+0] = f2bf(a.x); pk.h[c*4+1] = f2bf(a.y);
        pk.h[c*4+2] = f2bf(a.z); pk.h[c*4+3] = f2bf(a.w);
    }
    *(uint4*)(out + i) = pk.u;
}

// ---------------------------------------------------------------------------
// batched bf16 MFMA GEMM: C[M,N] = epi(A[M,K(lda)] @ Bt[N,K(ldb)]^T + bias)
// MODE 0: plain. MODE 1: A-row eye-gather (m>>8)*2048+(m&255).
// MODE 2: R-gemm slice z=(b,h): A+=(z>>3)*2048*512+(z&7)*64,
//         Bt+=(z>>3)*256*1024+(z&7)*64 (merged KWVb, ldb=1024), Cb+=z*2048*256.
// MODE 4: O-gemm batch: A+=z*2048*256 (Rb), Bt+=z*128*256 (VcatT interleaved).
// EPI 0: +bias. 1: +bias,gelu. 2: rcp(64+v). 4: fused attfin via shfl_xor(1):
//        col c=2d+s; att[row][h*64+d] = o0 + q*o1, bf16 into Cb (attb).
// ---------------------------------------------------------------------------
template<int BM, int BN, int MODE, int EPI, int OUTBF>
__global__ __launch_bounds__(256)
void bgemm_k(const u16* __restrict__ A, const u16* __restrict__ Bt,
             const float* __restrict__ bias, float* __restrict__ Cf,
             u16* __restrict__ Cb, int M, int N, int K,
             int lda, int ldb, int ldc, const u16* __restrict__ Qb)
{
    constexpr int WM = BM / 2, WN = BN / 2, FM = WM / 16, FN = WN / 16;
    __shared__ __align__(16) u16 As[BM][64];
    __shared__ __align__(16) u16 Bs[BN][64];
    const int z = blockIdx.z;
    if (MODE == 2) {
        A  += ((size_t)(z >> 3)) * (2048u * 512u)  + (size_t)(z & 7) * 64u;
        Bt += ((size_t)(z >> 3)) * (256u * 1024u)  + (size_t)(z & 7) * 64u;
        Cb += (size_t)z * (2048u * 256u);
    } else if (MODE == 4) {
        A  += (size_t)z * (2048u * 256u);
        Bt += (size_t)z * (128u * 256u);
    }
    const int tid  = threadIdx.x;
    const int lane = tid & 63, wid = tid >> 6;
    const int wr = wid >> 1, wc = wid & 1;
    const int m0 = blockIdx.y * BM, n0 = blockIdx.x * BN;

    f32x4 acc[FM][FN];
    #pragma unroll
    for (int i = 0; i < FM; ++i)
        #pragma unroll
        for (int j = 0; j < FN; ++j)
            acc[i][j] = (f32x4){0.f, 0.f, 0.f, 0.f};

    u16* ldsA = &As[0][0];
    u16* ldsB = &Bs[0][0];

    for (int k0 = 0; k0 < K; k0 += 64) {
        __syncthreads();
        #pragma unroll
        for (int it = 0; it < BM / 32; ++it) {          // BM*8/256 chunks
            const int f = it * 256 + tid;
            const int row = f >> 3, c8 = f & 7;
            int mrow = m0 + row;
            if (MODE == 1) mrow = (mrow >> 8) * 2048 + (mrow & 255);
            gload16(A + (size_t)mrow * lda + k0 + c8 * 8,
                    ldsA + (it * 256 + wid * 64) * 8);   // wave-uniform dest
        }
        #pragma unroll
        for (int it = 0; it < BN / 32; ++it) {
            const int f = it * 256 + tid;
            const int row = f >> 3, c8 = f & 7;
            gload16(Bt + (size_t)(n0 + row) * ldb + k0 + c8 * 8,
                    ldsB + (it * 256 + wid * 64) * 8);
        }
        __syncthreads();
        #pragma unroll
        for (int kk = 0; kk < 64; kk += 32) {
            bf16x8 af[FM], bfr[FN];
            const int kof  = kk + (lane >> 4) * 8;
            const int rsel = lane & 15;
            #pragma unroll
            for (int m = 0; m < FM; ++m)
                af[m] = *(const bf16x8*)&As[wr * WM + m * 16 + rsel][kof];
            #pragma unroll
            for (int n = 0; n < FN; ++n)
                bfr[n] = *(const bf16x8*)&Bs[wc * WN + n * 16 + rsel][kof];
            #pragma unroll
            for (int m = 0; m < FM; ++m)
                #pragma unroll
                for (int n = 0; n < FN; ++n)
                    acc[m][n] = __builtin_amdgcn_mfma_f32_16x16x32_bf16(
                        af[m], bfr[n], acc[m][n], 0, 0, 0);
        }
    }

    // C/D layout: col = lane&15, row = (lane>>4)*4 + j   [m89 verified]
    const int cl = lane & 15, r4 = (lane >> 4) * 4;

    if (EPI == 4) {
        // fused attfin: c = wc*WN + n*16 + cl = 2d+s; lanes cl, cl^1 hold (o0,o1)
        const int b = z >> 3, h = z & 7;
        #pragma unroll
        for (int n = 0; n < FN; ++n) {
            const int c = wc * WN + n * 16 + cl;
            const int d = c >> 1;
            #pragma unroll
            for (int m = 0; m < FM; ++m) {
                #pragma unroll
                for (int j = 0; j < 4; ++j) {
                    const int row = m0 + wr * WM + m * 16 + r4 + j;
                    const size_t gidx = ((size_t)(b * 2048 + row)) * 512 + h * 64 + d;
                    float o = acc[m][n][j];
                    float po = __shfl_xor(o, 1, 64);
                    if ((cl & 1) == 0)
                        Cb[gidx] = f2bf(o + bf2f(Qb[gidx]) * po);
                }
            }
        }
        return;
    }

    #pragma unroll
    for (int n = 0; n < FN; ++n) {
        const int col = n0 + wc * WN + n * 16 + cl;
        const float bv = (EPI <= 1) ? bias[col] : 0.f;
        #pragma unroll
        for (int m = 0; m < FM; ++m) {
            #pragma unroll
            for (int j = 0; j < 4; ++j) {
                const int row = m0 + wr * WM + m * 16 + r4 + j;
                float v = acc[m][n][j] + bv;
                if (EPI == 1)
                    v = 0.5f * v * (1.0f + erff(v * 0.70710678118654752f));
                if (EPI == 2)
                    v = __builtin_amdgcn_rcpf(64.0f + v);
                if (OUTBF) Cb[(size_t)row * ldc + col] = f2bf(v);
                else       Cf[(size_t)row * ldc + col] = v;
            }
        }
    }
}

// ---------------------------------------------------------------------------
// vcat (interleaved): VcatT[bh][2d+0][k] = V;  VcatT[bh][2d+1][k] = K'*V.
// Reads merged KWVb [512][1024]: cols 0..511 = K', 512..1023 = V.
// grid (4 kslices, 16 bh). Per block: 128 dcol x 64 k -> it<4.
// ---------------------------------------------------------------------------
__global__ __launch_bounds__(256)
void vcat_k(const u16* __restrict__ KWVb, u16* __restrict__ VcatT)
{
    __shared__ float tV[64][65];
    __shared__ float tK[64][65];
    const int ks = blockIdx.x, bh = blockIdx.y;
    const int b = bh >> 3, h = bh & 7;
    const int tid = threadIdx.x;

    #pragma unroll
    for (int it = 0; it < 2; ++it) {
        const int f = it * 256 + tid;
        const int r = f >> 3, c8 = (f & 7) * 8;
        const size_t src = ((size_t)(b * Kz + ks * 64 + r)) * 1024 + h * 64 + c8;
        bf16x8 k = *(const bf16x8*)(KWVb + src);
        bf16x8 v = *(const bf16x8*)(KWVb + src + 512);
        #pragma unroll
        for (int j = 0; j < 8; ++j) {
            tK[r][c8 + j] = bf2f((u16)k[j]);
            tV[r][c8 + j] = bf2f((u16)v[j]);
        }
    }
    __syncthreads();

    #pragma unroll
    for (int it = 0; it < 4; ++it) {
        const int f = it * 256 + tid;          // 0..1023
        const int dcol = f >> 3, k8 = (f & 7) * 8;
        const int d = dcol >> 1, s = dcol & 1;
        union { u16 h[8]; uint4 u; } pk;
        #pragma unroll
        for (int j = 0; j < 8; ++j) {
            const float V = tV[k8 + j][d];
            pk.h[j] = f2bf(s ? tK[k8 + j][d] * V : V);
        }
        *(uint4*)(VcatT + ((size_t)bh * 128 + dcol) * 256 + ks * 64 + k8) = pk.u;
    }
}

// ---------------------------------------------------------------------------
// fused residual-add + LayerNorm, fp32 out + bf16 out
// ---------------------------------------------------------------------------
__global__ __launch_bounds__(256)
void ln_k(const float* __restrict__ xin, const float* __restrict__ res,
          const float* __restrict__ g, const float* __restrict__ be,
          float* __restrict__ out, u16* __restrict__ outb)
{
    const int tid  = threadIdx.x;
    const int row  = blockIdx.x * 4 + (tid >> 6);
    const int lane = tid & 63;
    const size_t base = (size_t)row * 512 + lane * 8;

    float v[8];
    float s1 = 0.f, s2 = 0.f;
    #pragma unroll
    for (int c = 0; c < 2; ++c) {
        float4 a = *(const float4*)(xin + base + c * 4);
        float4 b = *(const float4*)(res + base + c * 4);
        float t0 = a.x + b.x, t1 = a.y + b.y, t2 = a.z + b.z, t3 = a.w + b.w;
        v[c*4+0] = t0; v[c*4+1] = t1; v[c*4+2] = t2; v[c*4+3] = t3;
        s1 += (t0 + t1) + (t2 + t3);
        s2 += (t0*t0 + t1*t1) + (t2*t2 + t3*t3);
    }
    #pragma unroll
    for (int off = 32; off >= 1; off >>= 1) {
        s1 += __shfl_xor(s1, off, 64);
        s2 += __shfl_xor(s2, off, 64);
    }
    const float mean = s1 * (1.f / 512.f);
    const float var  = s2 * (1.f / 512.f) - mean * mean;
    const float rs   = __builtin_amdgcn_rsqf(var + 1e-5f);

    union { u16 h[8]; uint4 u; } pk;
    #pragma unroll
    for (int c = 0; c < 2; ++c) {
        float4 gg = *(const float4*)(g  + lane * 8 + c * 4);
        float4 bb = *(const float4*)(be + lane * 8 + c * 4);
        float4 t;
        t.x = (v[c*4+0] - mean) * rs * gg.x + bb.x;
        t.y = (v[c*4+1] - mean) * rs * gg.y + bb.y;
        t.z = (v[c*4+2] - mean) * rs * gg.z + bb.z;
        t.w = (v[c*4+3] - mean) * rs * gg.w + bb.w;
        *(float4*)(out + base + c * 4) = t;
        pk.h[c*4+0] = f2bf(t.x); pk.h[c*4+1] = f2bf(t.y);
        pk.h[c*4+2] = f2bf(t.z); pk.h[c*4+3] = f2bf(t.w);
    }
    *(uint4*)(outb + base) = pk.u;
}

// ---------------------------------------------------------------------------
extern "C" void kernel_launch(void* const* d_in, const int* in_sizes, int n_in,
                              void* d_out, int out_size, void* d_ws, size_t ws_size,
                              hipStream_t stream)
{
    const float* xin  = (const float*)d_in[0];
    const float* to_q = (const float*)d_in[1];
    const float* to_k = (const float*)d_in[2];
    const float* to_v = (const float*)d_in[3];
    const float* wq   = (const float*)d_in[4];
    const float* bq   = (const float*)d_in[5];
    const float* wk   = (const float*)d_in[6];
    const float* bk   = (const float*)d_in[7];
    const float* wv   = (const float*)d_in[8];
    const float* bv   = (const float*)d_in[9];
    const float* wo   = (const float*)d_in[10];
    const float* bo   = (const float*)d_in[11];
    const float* g1   = (const float*)d_in[12];
    const float* be1  = (const float*)d_in[13];
    const float* w1   = (const float*)d_in[14];
    const float* bb1  = (const float*)d_in[15];
    const float* w2   = (const float*)d_in[16];
    const float* bb2  = (const float*)d_in[17];
    const float* g2   = (const float*)d_in[18];
    const float* be2  = (const float*)d_in[19];
    (void)in_sizes; (void)n_in; (void)out_size; (void)ws_size;

    float* p = (float*)d_ws;
    float* xcur = p;  p += XELEMS;
    float* xmid = p;  p += XELEMS;
    float* obuf = p;  p += XELEMS;                 // fp32 GEMM out (wo / ffn2)
    u16*  QWb16 = (u16*)p;  p += XELEMS / 2;
    u16*  KWVb  = (u16*)p;  p += (512 * 1024) / 2; // [512][1024]: K' | V
    u16*  hb    = (u16*)p;  p += XELEMS * 2;       // ffn hidden bf16; aliases Rb
    u16*  Rb    = hb;                              // [16][2048][256] bf16
    u16*  VcatT = (u16*)p;  p += (Bz * Hz * 128 * 256) / 2;  // interleaved
    u16*  attb  = (u16*)p;  p += XELEMS / 2;
    u16*  xb    = (u16*)p;  p += XELEMS / 2;
    u16*  xmidb = (u16*)p;  p += XELEMS / 2;
    u16*  WQcT  = (u16*)p;  p += (2 * Cz * Cz) / 2;        // per-layer
    u16*  WKVcT = (u16*)p;  p += (2 * Cz * 2 * Cz) / 2;    // per-layer [1024][512]
    u16*  woT   = (u16*)p;  p += (2 * Cz * Cz) / 2;
    u16*  w1T   = (u16*)p;  p += (2 * Cz * FFz) / 2;
    u16*  w2T   = (u16*)p;  p += (2 * Cz * FFz) / 2;
    float* bQc  = p;  p += 2 * Cz;
    float* bKVc = p;  p += 2 * 1024;

    const float sK = 0.125f;   // 1/sqrt(D) folded into K'

    // weight prep for BOTH layers, once
    combine3_k<<<6144, 256, 0, stream>>>(to_q, wq, bq, to_k, wk, bk, to_v, wv, bv,
                                         sK, WQcT, WKVcT, bQc, bKVc);
    tcast3_k<<<4608, 256, 0, stream>>>(wo, w1, w2, woT, w1T, w2T);
    castbf_k<<<1024, 256, 0, stream>>>(xin, xb);

    for (int l = 0; l < Lz; ++l) {
        const float* xl   = (l == 0) ? xin : xcur;
        float*       xout = (l == Lz - 1) ? (float*)d_out : xcur;

        // Q projection (M=4096) and merged K|V projection (M=512 gather, N=1024)
        bgemm_k<64,64,0,0,1><<<dim3(8,64,1), 256, 0, stream>>>(
            xb, WQcT + l*262144, bQc + l*512, nullptr, QWb16,
            4096, 512, 512, 512, 512, 512, nullptr);
        bgemm_k<64,64,1,0,1><<<dim3(16,8,1), 256, 0, stream>>>(
            xb, WKVcT + l*524288, bKVc + l*1024, nullptr, KWVb,
            512, 1024, 512, 512, 512, 1024, nullptr);

        // Taylor-1 channel-softmax attention:
        //   R = 1/(64 + QW @ K'^T);  att = R@V + q .* (R@(K'.V))  [fused epilogue]
        vcat_k<<<dim3(4,16), 256, 0, stream>>>(KWVb, VcatT);
        bgemm_k<64,64,2,2,1><<<dim3(4,32,16), 256, 0, stream>>>(
            QWb16, KWVb, nullptr, nullptr, Rb,
            2048, 256, 64, 512, 1024, 256, nullptr);
        bgemm_k<64,128,4,4,1><<<dim3(1,32,16), 256, 0, stream>>>(
            Rb, VcatT, nullptr, nullptr, attb,
            2048, 128, 256, 256, 256, 512, QWb16);

        bgemm_k<64,64,0,0,0><<<dim3(8,64,1), 256, 0, stream>>>(
            attb, woT + l*262144, bo + l*512, obuf, nullptr,
            4096, 512, 512, 512, 512, 512, nullptr);
        ln_k<<<1024, 256, 0, stream>>>(obuf, xl, g1 + l*512, be1 + l*512, xmid, xmidb);

        bgemm_k<128,128,0,1,1><<<dim3(16,32,1), 256, 0, stream>>>(
            xmidb, w1T + l*1048576, bb1 + l*2048, nullptr, hb,
            4096, 2048, 512, 512, 512, 2048, nullptr);
        bgemm_k<64,64,0,0,0><<<dim3(8,64,1), 256, 0, stream>>>(
            hb, w2T + l*1048576, bb2 + l*512, obuf, nullptr,
            4096, 512, 2048, 2048, 2048, 512, nullptr);
        ln_k<<<1024, 256, 0, stream>>>(obuf, xmid, g2 + l*512, be2 + l*512, xout, xb);
    }
}